// Round 4
// baseline (5179.919 us; speedup 1.0000x reference)
//
#include <hip/hip_runtime.h>

#define T_SEQ 512
#define HID   50
#define KH    28      // K-half width: 2*28=56 covers K=50 with 6 zero pads
#define HP    56      // padded hidden vector length (float4-aligned, 224B rows)
#define GPW   52      // partial-sum buffer inner stride
#define BBLK  4       // batch rows per block
#define BLK   512     // 8 waves = 4 gates x 2 K-halves
#define XW    32      // x staging window (timesteps)

typedef float v4f __attribute__((ext_vector_type(4)));
typedef float v2f __attribute__((ext_vector_type(2)));

#define REP7(F) F(0) F(1) F(2) F(3) F(4) F(5) F(6)

// 21 named v4f = 84 VGPRs of weights per thread. Split-K exists precisely so
// this fits the 128-VGPR budget the compiler has pinned us to for 3 rounds
// (VGPR_Count=128 + scratch traffic with 150 wt floats/thread; waves_per_eu
// hints never lifted it).
#define DECLW(i) v4f w0_##i, wa_##i, wb_##i;

#define WELT(P, kk) (((koff + (kk)) < HID) ? (P)[koff + (kk)] : 0.f)

#define LDW(i) \
  w0_##i = (v4f){WELT(pW0,4*(i)), WELT(pW0,4*(i)+1), WELT(pW0,4*(i)+2), WELT(pW0,4*(i)+3)}; \
  wa_##i = (v4f){WELT(pWa,4*(i)), WELT(pWa,4*(i)+1), WELT(pWa,4*(i)+2), WELT(pWa,4*(i)+3)}; \
  wb_##i = (v4f){WELT(pWb,4*(i)), WELT(pWb,4*(i)+1), WELT(pWb,4*(i)+2), WELT(pWb,4*(i)+3)};

// one 16B chunk of the half-row matvec for 4 batch rows; v2f halves ->
// v_pk_fma_f32 (2 fp32 MACs/instr)
#define MV(W, HB, i) { \
  const v4f h0 = *(const v4f*)((HB) + 0*HP + 4*(i)); \
  const v4f h1 = *(const v4f*)((HB) + 1*HP + 4*(i)); \
  const v4f h2 = *(const v4f*)((HB) + 2*HP + 4*(i)); \
  const v4f h3 = *(const v4f*)((HB) + 3*HP + 4*(i)); \
  acc0 = __builtin_elementwise_fma(W##_##i.lo, h0.lo, acc0); \
  acc0 = __builtin_elementwise_fma(W##_##i.hi, h0.hi, acc0); \
  acc1 = __builtin_elementwise_fma(W##_##i.lo, h1.lo, acc1); \
  acc1 = __builtin_elementwise_fma(W##_##i.hi, h1.hi, acc1); \
  acc2 = __builtin_elementwise_fma(W##_##i.lo, h2.lo, acc2); \
  acc2 = __builtin_elementwise_fma(W##_##i.hi, h2.hi, acc2); \
  acc3 = __builtin_elementwise_fma(W##_##i.lo, h3.lo, acc3); \
  acc3 = __builtin_elementwise_fma(W##_##i.hi, h3.hi, acc3); }

#define MV_W0(i) MV(w0, hA0, i)
#define MV_WA(i) MV(wa, hA0, i)
#define MV_WB(i) MV(wb, hB0, i)

__device__ __forceinline__ float sigm_f(float x) {
    return __builtin_amdgcn_rcpf(1.f + __expf(-x));
}
__device__ __forceinline__ float tanh_f(float x) {
    return fmaf(2.f, __builtin_amdgcn_rcpf(1.f + __expf(-2.f * x)), -1.f);
}

__global__ __launch_bounds__(BLK)
__attribute__((amdgpu_waves_per_eu(4)))   // pin the observed 128-VGPR / 4-waves-per-SIMD point
void lstm2_fused(const float* __restrict__ x,
                 const float* __restrict__ Wih0,
                 const float* __restrict__ Whh0,
                 const float* __restrict__ bih0,
                 const float* __restrict__ bhh0,
                 const float* __restrict__ Wih1,
                 const float* __restrict__ Whh1,
                 const float* __restrict__ bih1,
                 const float* __restrict__ bhh1,
                 const float* __restrict__ Wfc,
                 const float* __restrict__ bfc,
                 float* __restrict__ out)
{
    __shared__ __align__(16) float hA[BBLK][HP];          // layer0 hidden (pads stay 0)
    __shared__ __align__(16) float hB[BBLK][HP];          // layer1 hidden
    __shared__ float gp0[4 * 2 * BBLK * GPW];             // layer0 gate partials [gt][half][b][n]
    __shared__ float gp1[4 * 2 * BBLK * GPW];             // layer1 gate partials
    __shared__ __align__(16) v4f xs4[XW];                 // x window, xs4[t&31][b]

    const int tid    = threadIdx.x;
    const int w      = tid >> 6;        // wave id
    const int gt     = w & 3;           // gate (i,f,g,o)
    const int halfid = w >> 2;          // K-half
    const int lane   = tid & 63;
    const int bb0    = blockIdx.x * BBLK;
    const bool on    = (lane < HID);
    const int  n     = on ? lane : (HID - 1);
    const int  j     = gt * HID + n;    // gate-output row in [0,200)
    const int  koff  = halfid * KH;     // this wave's K-offset (0 or 28)

    // zero h buffers; stage x for t=0..31
    for (int i = tid; i < BBLK * HP; i += BLK) {
        (&hA[0][0])[i] = 0.0f;
        (&hB[0][0])[i] = 0.0f;
    }
    if (tid >= 256 && tid < 256 + BBLK * XW) {
        int q = tid - 256, i2 = q >> 2, b = q & 3;
        ((float*)&xs4[i2])[b] = x[(long)(bb0 + b) * T_SEQ + i2];
    }
    __syncthreads();

    // ---- per-thread half-row weights into (SSA) registers ----
    const float* pW0 = Whh0 + j * HID;
    const float* pWa = Wih1 + j * HID;
    const float* pWb = Whh1 + j * HID;
    DECLW(0) DECLW(1) DECLW(2) DECLW(3) DECLW(4) DECLW(5) DECLW(6)
    REP7(LDW)

    // bias + x terms counted once: only half 0 carries them
    const float wx  = (halfid == 0) ? Wih0[j] : 0.f;
    const float b0j = (halfid == 0) ? (bih0[j] + bhh0[j]) : 0.f;
    const float b1j = (halfid == 0) ? (bih1[j] + bhh1[j]) : 0.f;

    const float* hA0 = &hA[0][koff];
    const float* hB0 = &hB[0][koff];
    float* gpw0 = &gp0[((gt * 2 + halfid) * BBLK) * GPW + lane];
    float* gpw1 = &gp1[((gt * 2 + halfid) * BBLK) * GPW + lane];

    float cA = 0.f, cB = 0.f;   // cell states owned by waves 0-3 (wave=batch, lane=unit)

    #pragma clang loop unroll(disable)
    for (int t = 0; t < T_SEQ; ++t) {
        // ===== ph1 (all 8 waves): layer0 half-matvec -> gp0 =====
        const v4f xv = xs4[t & (XW - 1)];
        v2f acc0 = (v2f){fmaf(wx, xv.x, b0j), 0.f};
        v2f acc1 = (v2f){fmaf(wx, xv.y, b0j), 0.f};
        v2f acc2 = (v2f){fmaf(wx, xv.z, b0j), 0.f};
        v2f acc3 = (v2f){fmaf(wx, xv.w, b0j), 0.f};
        REP7(MV_W0)
        if (on) {
            gpw0[0 * GPW] = acc0.x + acc0.y;
            gpw0[1 * GPW] = acc1.x + acc1.y;
            gpw0[2 * GPW] = acc2.x + acc2.y;
            gpw0[3 * GPW] = acc3.x + acc3.y;
        }
        __syncthreads();   // B1: gp0 complete

        // ===== ph2: waves 0-3 update layer0; waves 4-7 stage next x window =====
        if (w < 4) {
            if (on) {
                float gi = gp0[((0*2+0)*BBLK + w)*GPW + lane] + gp0[((0*2+1)*BBLK + w)*GPW + lane];
                float gf = gp0[((1*2+0)*BBLK + w)*GPW + lane] + gp0[((1*2+1)*BBLK + w)*GPW + lane];
                float gg = gp0[((2*2+0)*BBLK + w)*GPW + lane] + gp0[((2*2+1)*BBLK + w)*GPW + lane];
                float go = gp0[((3*2+0)*BBLK + w)*GPW + lane] + gp0[((3*2+1)*BBLK + w)*GPW + lane];
                gi = sigm_f(gi); gf = sigm_f(gf); gg = tanh_f(gg); go = sigm_f(go);
                cA = fmaf(gf, cA, gi * gg);
                hA[w][lane] = go * tanh_f(cA);
            }
        } else if ((t & (XW - 1)) == (XW - 1)) {
            int q = tid - 256;
            if (q < BBLK * XW) {
                int i2 = q >> 2, b = q & 3, tt = t + 1 + i2;
                if (tt < T_SEQ)
                    ((float*)&xs4[i2])[b] = x[(long)(bb0 + b) * T_SEQ + tt];
            }
            // xs next read at ph1(t+1): B2 intervenes. OK.
        }
        __syncthreads();   // B2: hA(t) + xs window complete

        // ===== ph3 (all 8 waves): layer1 half-matvec -> gp1 =====
        acc0 = (v2f){b1j, 0.f};
        acc1 = (v2f){b1j, 0.f};
        acc2 = (v2f){b1j, 0.f};
        acc3 = (v2f){b1j, 0.f};
        REP7(MV_WA)
        REP7(MV_WB)
        if (on) {
            gpw1[0 * GPW] = acc0.x + acc0.y;
            gpw1[1 * GPW] = acc1.x + acc1.y;
            gpw1[2 * GPW] = acc2.x + acc2.y;
            gpw1[3 * GPW] = acc3.x + acc3.y;
        }
        __syncthreads();   // B3: gp1 complete

        // ===== ph4: waves 0-3 update layer1 (no trailing barrier) =====
        // hazards: hB written here is next read in ph3(t+1)  [B1,B2 intervene];
        // gp1 read here is next written in ph3(t+1)          [B1,B2 intervene];
        // gp0 written in ph1(t+1) was last read in ph2(t)    [B2,B3 intervene];
        // hA read in ph1(t+1) was written in ph2(t)          [B2,B3 intervene].
        if (w < 4 && on) {
            float gi = gp1[((0*2+0)*BBLK + w)*GPW + lane] + gp1[((0*2+1)*BBLK + w)*GPW + lane];
            float gf = gp1[((1*2+0)*BBLK + w)*GPW + lane] + gp1[((1*2+1)*BBLK + w)*GPW + lane];
            float gg = gp1[((2*2+0)*BBLK + w)*GPW + lane] + gp1[((2*2+1)*BBLK + w)*GPW + lane];
            float go = gp1[((3*2+0)*BBLK + w)*GPW + lane] + gp1[((3*2+1)*BBLK + w)*GPW + lane];
            gi = sigm_f(gi); gf = sigm_f(gf); gg = tanh_f(gg); go = sigm_f(go);
            cB = fmaf(gf, cB, gi * gg);
            hB[w][lane] = go * tanh_f(cB);
        }
    }
    __syncthreads();   // final hB visible to classifier

    // ===== classifier: out[b][c] = hB[b] . Wfc[c] + bfc[c] =====
    if (tid < BBLK * 2) {
        const int b = tid >> 1;
        const int c = tid & 1;
        float a = bfc[c];
        #pragma unroll
        for (int k = 0; k < HID; ++k)
            a = fmaf(Wfc[c * HID + k], hB[b][k], a);
        out[(bb0 + b) * 2 + c] = a;
    }
}

extern "C" void kernel_launch(void* const* d_in, const int* in_sizes, int n_in,
                              void* d_out, int out_size, void* d_ws, size_t ws_size,
                              hipStream_t stream) {
    const float* x    = (const float*)d_in[0];
    const float* Wih0 = (const float*)d_in[1];
    const float* Whh0 = (const float*)d_in[2];
    const float* bih0 = (const float*)d_in[3];
    const float* bhh0 = (const float*)d_in[4];
    const float* Wih1 = (const float*)d_in[5];
    const float* Whh1 = (const float*)d_in[6];
    const float* bih1 = (const float*)d_in[7];
    const float* bhh1 = (const float*)d_in[8];
    const float* Wfc  = (const float*)d_in[9];
    const float* bfc  = (const float*)d_in[10];
    float* out = (float*)d_out;

    const int B = in_sizes[0] / T_SEQ;     // D == 1
    const int grid = B / BBLK;             // 2048/4 = 512 blocks

    hipLaunchKernelGGL(lstm2_fused, dim3(grid), dim3(BLK), 0, stream,
                       x, Wih0, Whh0, bih0, bhh0, Wih1, Whh1, bih1, bhh1,
                       Wfc, bfc, out);
}

// Round 5
// 1360.152 us; speedup vs baseline: 3.8083x; 3.8083x over previous
//
#include <hip/hip_runtime.h>

#define T_SEQ 512
#define HID   50
#define NB    16          // batch rows per block (MFMA N)
#define BLK   256         // 4 waves
#define GS    213         // gbuf row stride in floats (odd => conflict-free b32)

typedef float v4f  __attribute__((ext_vector_type(4)));
typedef _Float16 f16;
typedef f16  f16x8 __attribute__((ext_vector_type(8)));

// M layout: 4 gates x 52 rows (50 units + 2 pad) = 208 rows = 13 Mtiles of 16.
// Layer0 A (reg-resident): K=64: cols 0..49 = Whh0, col 62 = Wih0 (wx), col 63 = b0.
// Layer1 Aa (reg-resident): K=64: cols 0..49 = Wih1, col 63 = b1.
// Layer1 Ab (LDS):          K=64: cols 0..49 = Whh1.
// B (LDS, f16): k 0..49 = hA, k62 = x(t), k63 = 1.0, k 64..113 = hB.
// MFMA 16x16x32_f16 layouts (guide §3, m89/m91/m120-verified):
//   A: lane holds A[m=lane&15][k = (lane>>4)*8 + j]
//   B: lane holds B[k = (lane>>4)*8 + j][n=lane&15]
//   C: lane reg r holds C[row=(lane>>4)*4+r][col=lane&15]

__device__ __forceinline__ f16x8 ldA0(const float* __restrict__ Whh0,
                                      const float* __restrict__ Wih0,
                                      const float* __restrict__ bih0,
                                      const float* __restrict__ bhh0,
                                      int m, int kb) {
    const int g = m / 52, r = m - 52 * g;
    f16x8 v;
    #pragma unroll
    for (int j = 0; j < 8; ++j) {
        const int k = kb + j;
        float f = 0.f;
        if (r < HID) {
            const int rho = 50 * g + r;
            if (k < HID)      f = Whh0[rho * HID + k];
            else if (k == 62) f = Wih0[rho];
            else if (k == 63) f = bih0[rho] + bhh0[rho];
        }
        v[j] = (f16)f;
    }
    return v;
}

__device__ __forceinline__ f16x8 ldA1a(const float* __restrict__ Wih1,
                                       const float* __restrict__ bih1,
                                       const float* __restrict__ bhh1,
                                       int m, int kb) {
    const int g = m / 52, r = m - 52 * g;
    f16x8 v;
    #pragma unroll
    for (int j = 0; j < 8; ++j) {
        const int k = kb + j;
        float f = 0.f;
        if (r < HID) {
            const int rho = 50 * g + r;
            if (k < HID)      f = Wih1[rho * HID + k];
            else if (k == 63) f = bih1[rho] + bhh1[rho];
        }
        v[j] = (f16)f;
    }
    return v;
}

__global__ __launch_bounds__(BLK, 1)   // 1 block/CU (grid=128): give allocator full VGPR room
void lstm2_mfma(const float* __restrict__ x,
                const float* __restrict__ Wih0,
                const float* __restrict__ Whh0,
                const float* __restrict__ bih0,
                const float* __restrict__ bhh0,
                const float* __restrict__ Wih1,
                const float* __restrict__ Whh1,
                const float* __restrict__ bih1,
                const float* __restrict__ bhh1,
                const float* __restrict__ Wfc,
                const float* __restrict__ bfc,
                float* __restrict__ out)
{
    __shared__ __align__(16) f16 AP1b[13 * 2 * 64 * 8];   // 26,624 B: Whh1 frags
    __shared__ __align__(16) f16 BPH [4 * 64 * 8];        //  4,096 B: B frags (h/x/1)
    __shared__ float gbuf0[NB * GS];                      // 13,632 B: layer0 preacts
    __shared__ float gbuf1[NB * GS];                      // 13,632 B: layer1 preacts

    const int tid  = threadIdx.x;
    const int w    = tid >> 6;
    const int lane = tid & 63;
    const int n16  = lane & 15;
    const int quad = lane >> 4;
    const int bb0  = blockIdx.x * NB;
    const int nmt  = (w == 0) ? 4 : 3;              // Mtiles per wave: {4,3,3,3}
    const int mtb  = (w == 0) ? 0 : (3 * w + 1);    // first Mtile: 0,4,7,10

    const float* xg = x + (long)bb0 * T_SEQ;

    // ---- one-time: zero B buffer; pack Whh1 frags into LDS ----
    for (int i = tid; i < 4 * 64 * 8; i += BLK) BPH[i] = (f16)0.f;
    for (int s = tid; s < 13 * 2 * 64; s += BLK) {
        const int mt = s >> 7;
        const int kt = (s >> 6) & 1;
        const int l  = s & 63;
        const int m  = mt * 16 + (l & 15);
        const int kb = kt * 32 + (l >> 4) * 8;
        const int g  = m / 52, r = m - 52 * g;
        f16x8 v;
        #pragma unroll
        for (int j = 0; j < 8; ++j) {
            const int k = kb + j;
            float f = 0.f;
            if (r < HID && k < HID) f = Whh1[(50 * g + r) * HID + k];
            v[j] = (f16)f;
        }
        ((f16x8*)AP1b)[s] = v;
    }

    // ---- one-time: A0 / A1a fragments into named SSA registers ----
    f16x8 a00_0, a00_1, a00_2, a00_3;   // layer0, ktile 0
    f16x8 a01_0, a01_1, a01_2, a01_3;   // layer0, ktile 1
    f16x8 aa0_0, aa0_1, aa0_2, aa0_3;   // layer1a, ktile 0
    f16x8 aa1_0, aa1_1, aa1_2, aa1_3;   // layer1a, ktile 1
    {
        const int m = (mtb) * 16 + n16;
        const int kb0 = quad * 8, kb1 = 32 + quad * 8;
        a00_0 = ldA0(Whh0, Wih0, bih0, bhh0, m, kb0);
        a01_0 = ldA0(Whh0, Wih0, bih0, bhh0, m, kb1);
        aa0_0 = ldA1a(Wih1, bih1, bhh1, m, kb0);
        aa1_0 = ldA1a(Wih1, bih1, bhh1, m, kb1);
    }
    {
        const int m = (mtb + 1) * 16 + n16;
        const int kb0 = quad * 8, kb1 = 32 + quad * 8;
        a00_1 = ldA0(Whh0, Wih0, bih0, bhh0, m, kb0);
        a01_1 = ldA0(Whh0, Wih0, bih0, bhh0, m, kb1);
        aa0_1 = ldA1a(Wih1, bih1, bhh1, m, kb0);
        aa1_1 = ldA1a(Wih1, bih1, bhh1, m, kb1);
    }
    {
        const int m = (mtb + 2) * 16 + n16;
        const int kb0 = quad * 8, kb1 = 32 + quad * 8;
        a00_2 = ldA0(Whh0, Wih0, bih0, bhh0, m, kb0);
        a01_2 = ldA0(Whh0, Wih0, bih0, bhh0, m, kb1);
        aa0_2 = ldA1a(Wih1, bih1, bhh1, m, kb0);
        aa1_2 = ldA1a(Wih1, bih1, bhh1, m, kb1);
    }
    if (3 < nmt) {
        const int m = (mtb + 3) * 16 + n16;
        const int kb0 = quad * 8, kb1 = 32 + quad * 8;
        a00_3 = ldA0(Whh0, Wih0, bih0, bhh0, m, kb0);
        a01_3 = ldA0(Whh0, Wih0, bih0, bhh0, m, kb1);
        aa0_3 = ldA1a(Wih1, bih1, bhh1, m, kb0);
        aa1_3 = ldA1a(Wih1, bih1, bhh1, m, kb1);
    }

    __syncthreads();
    // specials in B: k=63 -> 1.0 (bias lane), k=62 -> x(0)
    if (tid < NB) {
        BPH[(64 + 48 + tid) * 8 + 7] = (f16)1.f;
        BPH[(64 + 48 + tid) * 8 + 6] = (f16)xg[tid * T_SEQ + 0];
    }
    __syncthreads();

    float cA0 = 0.f, cA1 = 0.f, cA2 = 0.f, cA3 = 0.f;
    float cB0 = 0.f, cB1 = 0.f, cB2 = 0.f, cB3 = 0.f;
    const f16x8* BPF = (const f16x8*)BPH;
    const f16x8* APF = (const f16x8*)AP1b;

#define MFMA16(A, B, C) __builtin_amdgcn_mfma_f32_16x16x32_f16((A), (B), (C), 0, 0, 0)

#define P0MT(I) if ((I) < nmt) { \
    v4f C = {0.f, 0.f, 0.f, 0.f}; \
    C = MFMA16(a00_##I, B0, C); \
    C = MFMA16(a01_##I, B1, C); \
    float* gp = gbuf0 + n16 * GS + (mtb + (I)) * 16 + quad * 4; \
    gp[0] = C[0]; gp[1] = C[1]; gp[2] = C[2]; gp[3] = C[3]; }

#define P2MT(I) if ((I) < nmt) { \
    v4f C = {0.f, 0.f, 0.f, 0.f}; \
    C = MFMA16(aa0_##I, B0, C); \
    C = MFMA16(aa1_##I, B1, C); \
    f16x8 Ab0 = APF[((mtb + (I)) * 2 + 0) * 64 + lane]; \
    f16x8 Ab1 = APF[((mtb + (I)) * 2 + 1) * 64 + lane]; \
    C = MFMA16(Ab0, B2, C); \
    C = MFMA16(Ab1, B3, C); \
    float* gp = gbuf1 + n16 * GS + (mtb + (I)) * 16 + quad * 4; \
    gp[0] = C[0]; gp[1] = C[1]; gp[2] = C[2]; gp[3] = C[3]; }

    // update: p-th (unit,batch) pair; preacts are COMPLETE (bias/x folded into MFMA)
#define UPD(S, GB, CS, KOFF, STASH) { \
    const int p = tid + 256 * (S); \
    if (p < 800) { \
        const int uu = p >> 4, nn = p & 15; \
        const float qi = GB[nn * GS +        uu]; \
        const float qf = GB[nn * GS +  52 +  uu]; \
        const float qg = GB[nn * GS + 104 +  uu]; \
        const float qo = GB[nn * GS + 156 +  uu]; \
        const float gi = 1.f / (1.f + __expf(-qi)); \
        const float gf = 1.f / (1.f + __expf(-qf)); \
        const float gg = 2.f / (1.f + __expf(-2.f * qg)) - 1.f; \
        const float go = 1.f / (1.f + __expf(-qo)); \
        CS = fmaf(gf, CS, gi * gg); \
        const float hh = go * (2.f / (1.f + __expf(-2.f * CS)) - 1.f); \
        const int k = (KOFF) + uu; \
        BPH[((k >> 5) * 64 + ((k & 31) >> 3) * 16 + nn) * 8 + (k & 7)] = (f16)hh; \
        STASH \
    } }

    #pragma clang loop unroll(disable)
    for (int t = 0; t < T_SEQ; ++t) {
        // ---- P0: layer0 preacts = [Whh0|wx|b0] @ [hA(t-1);x(t);1] -> gbuf0 ----
        {
            f16x8 B0 = BPF[0 * 64 + lane];
            f16x8 B1 = BPF[1 * 64 + lane];
            P0MT(0) P0MT(1) P0MT(2) P0MT(3)
        }
        __syncthreads();   // B1: gbuf0 complete

        // ---- P1: layer0 update -> hA(t) into B slots k=0..49; prefetch x(t+1) ----
        UPD(0, gbuf0, cA0, 0, {})
        UPD(1, gbuf0, cA1, 0, {})
        UPD(2, gbuf0, cA2, 0, {})
        UPD(3, gbuf0, cA3, 0, {})
        if (tid < NB && t < T_SEQ - 1)
            BPH[(64 + 48 + tid) * 8 + 6] = (f16)xg[tid * T_SEQ + t + 1];
        __syncthreads();   // B2: hA(t), x(t+1) visible

        // ---- P2: layer1 preacts = [Wih1|b1]@[hA(t);..;1] + Whh1@hB(t-1) -> gbuf1 ----
        {
            f16x8 B0 = BPF[0 * 64 + lane];
            f16x8 B1 = BPF[1 * 64 + lane];
            f16x8 B2 = BPF[2 * 64 + lane];
            f16x8 B3 = BPF[3 * 64 + lane];
            P2MT(0) P2MT(1) P2MT(2) P2MT(3)
        }
        __syncthreads();   // B3: gbuf1 complete

        // ---- P3: layer1 update -> hB(t) into B slots k=64..113 (no trailing barrier:
        //      next P0 touches only gbuf0/kt0-1-reads; gbuf1 WAR covered by B1,B2(t+1)) ----
        UPD(0, gbuf1, cB0, 64, { if (t == T_SEQ - 1) gbuf0[nn * GS + uu] = hh; })
        UPD(1, gbuf1, cB1, 64, { if (t == T_SEQ - 1) gbuf0[nn * GS + uu] = hh; })
        UPD(2, gbuf1, cB2, 64, { if (t == T_SEQ - 1) gbuf0[nn * GS + uu] = hh; })
        UPD(3, gbuf1, cB3, 64, { if (t == T_SEQ - 1) gbuf0[nn * GS + uu] = hh; })
    }
    __syncthreads();   // final fp32 hB (stashed in gbuf0) visible

    // ---- classifier: out[n][c] = hB[n] . Wfc[c] + bfc[c] ----
    if (tid < NB * 2) {
        const int nn = tid >> 1, c = tid & 1;
        float acc = bfc[c];
        #pragma unroll
        for (int u = 0; u < HID; ++u)
            acc = fmaf(Wfc[c * HID + u], gbuf0[nn * GS + u], acc);
        out[(bb0 + nn) * 2 + c] = acc;
    }
}

extern "C" void kernel_launch(void* const* d_in, const int* in_sizes, int n_in,
                              void* d_out, int out_size, void* d_ws, size_t ws_size,
                              hipStream_t stream) {
    const float* x    = (const float*)d_in[0];
    const float* Wih0 = (const float*)d_in[1];
    const float* Whh0 = (const float*)d_in[2];
    const float* bih0 = (const float*)d_in[3];
    const float* bhh0 = (const float*)d_in[4];
    const float* Wih1 = (const float*)d_in[5];
    const float* Whh1 = (const float*)d_in[6];
    const float* bih1 = (const float*)d_in[7];
    const float* bhh1 = (const float*)d_in[8];
    const float* Wfc  = (const float*)d_in[9];
    const float* bfc  = (const float*)d_in[10];
    float* out = (float*)d_out;

    const int B = in_sizes[0] / T_SEQ;   // D == 1
    const int grid = B / NB;             // 2048/16 = 128 blocks

    hipLaunchKernelGGL(lstm2_mfma, dim3(grid), dim3(BLK), 0, stream,
                       x, Wih0, Whh0, bih0, bhh0, Wih1, Whh1, bih1, bhh1,
                       Wfc, bfc, out);
}

// Round 6
// 803.117 us; speedup vs baseline: 6.4498x; 1.6936x over previous
//
#include <hip/hip_runtime.h>

#define T_SEQ 512
#define HID   50
#define NB    4           // batch rows per block (MFMA N=16, 4 valid cols)
#define BLK   256         // 4 waves
#define GS    213         // gbuf row stride in floats (odd => conflict-light b32)

typedef float v4f  __attribute__((ext_vector_type(4)));
typedef _Float16 f16;
typedef f16  f16x8 __attribute__((ext_vector_type(8)));

// M layout: 4 gates x 52 rows (50 units + 2 pad) = 208 rows = 13 Mtiles of 16.
// Layer0 A (reg-resident): K=64: cols 0..49 = Whh0, col 62 = Wih0 (wx), col 63 = b0.
// Layer1 Aa (reg-resident): K=64: cols 0..49 = Wih1, col 63 = b1.
// Layer1 Ab (LDS):          K=64: cols 0..49 = Whh1.
// B (LDS, f16): k 0..49 = hA, k62 = x(t), k63 = 1.0, k 64..113 = hB.
// MFMA 16x16x32_f16 layouts (m89/m91-verified; numerically validated in R5):
//   A: lane holds A[m=lane&15][k=(lane>>4)*8+j]
//   B: lane holds B[k=(lane>>4)*8+j][n=lane&15]
//   C: lane reg r holds C[row=(lane>>4)*4+r][col=lane&15]
// R6 change vs R5: NB 16->4, grid 128->512 => 2 blocks/CU co-resident
// (75KB LDS/CU, 2 waves/SIMD). R5 evidence: Occupancy=6% (1 wave/SIMD,
// half the CUs idle) made the 6200cyc/step critical path pure exposed latency.

__device__ __forceinline__ f16x8 ldA0(const float* __restrict__ Whh0,
                                      const float* __restrict__ Wih0,
                                      const float* __restrict__ bih0,
                                      const float* __restrict__ bhh0,
                                      int m, int kb) {
    const int g = m / 52, r = m - 52 * g;
    f16x8 v;
    #pragma unroll
    for (int j = 0; j < 8; ++j) {
        const int k = kb + j;
        float f = 0.f;
        if (r < HID) {
            const int rho = 50 * g + r;
            if (k < HID)      f = Whh0[rho * HID + k];
            else if (k == 62) f = Wih0[rho];
            else if (k == 63) f = bih0[rho] + bhh0[rho];
        }
        v[j] = (f16)f;
    }
    return v;
}

__device__ __forceinline__ f16x8 ldA1a(const float* __restrict__ Wih1,
                                       const float* __restrict__ bih1,
                                       const float* __restrict__ bhh1,
                                       int m, int kb) {
    const int g = m / 52, r = m - 52 * g;
    f16x8 v;
    #pragma unroll
    for (int j = 0; j < 8; ++j) {
        const int k = kb + j;
        float f = 0.f;
        if (r < HID) {
            const int rho = 50 * g + r;
            if (k < HID)      f = Wih1[rho * HID + k];
            else if (k == 63) f = bih1[rho] + bhh1[rho];
        }
        v[j] = (f16)f;
    }
    return v;
}

__global__ __launch_bounds__(BLK, 1)   // same allocator-proven shape as R5 (88 VGPR, no spill)
void lstm2_mfma(const float* __restrict__ x,
                const float* __restrict__ Wih0,
                const float* __restrict__ Whh0,
                const float* __restrict__ bih0,
                const float* __restrict__ bhh0,
                const float* __restrict__ Wih1,
                const float* __restrict__ Whh1,
                const float* __restrict__ bih1,
                const float* __restrict__ bhh1,
                const float* __restrict__ Wfc,
                const float* __restrict__ bfc,
                float* __restrict__ out)
{
    __shared__ __align__(16) f16 AP1b[13 * 2 * 64 * 8];   // 26,624 B: Whh1 frags
    __shared__ __align__(16) f16 BPH [4 * 64 * 8];        //  4,096 B: B frags (h/x/1)
    __shared__ float gbuf0[NB * GS];                      //  3,408 B: layer0 preacts
    __shared__ float gbuf1[NB * GS];                      //  3,408 B: layer1 preacts

    const int tid  = threadIdx.x;
    const int w    = tid >> 6;
    const int lane = tid & 63;
    const int n16  = lane & 15;
    const int quad = lane >> 4;
    const int bb0  = blockIdx.x * NB;
    const int nmt  = (w == 0) ? 4 : 3;              // Mtiles per wave: {4,3,3,3}
    const int mtb  = (w == 0) ? 0 : (3 * w + 1);    // first Mtile: 0,4,7,10

    const float* xg = x + (long)bb0 * T_SEQ;

    // ---- one-time: zero B buffer; pack Whh1 frags into LDS ----
    for (int i = tid; i < 4 * 64 * 8; i += BLK) BPH[i] = (f16)0.f;
    for (int s = tid; s < 13 * 2 * 64; s += BLK) {
        const int mt = s >> 7;
        const int kt = (s >> 6) & 1;
        const int l  = s & 63;
        const int m  = mt * 16 + (l & 15);
        const int kb = kt * 32 + (l >> 4) * 8;
        const int g  = m / 52, r = m - 52 * g;
        f16x8 v;
        #pragma unroll
        for (int j = 0; j < 8; ++j) {
            const int k = kb + j;
            float f = 0.f;
            if (r < HID && k < HID) f = Whh1[(50 * g + r) * HID + k];
            v[j] = (f16)f;
        }
        ((f16x8*)AP1b)[s] = v;
    }

    // ---- one-time: A0 / A1a fragments into named SSA registers ----
    f16x8 a00_0, a00_1, a00_2, a00_3;   // layer0, ktile 0
    f16x8 a01_0, a01_1, a01_2, a01_3;   // layer0, ktile 1
    f16x8 aa0_0, aa0_1, aa0_2, aa0_3;   // layer1a, ktile 0
    f16x8 aa1_0, aa1_1, aa1_2, aa1_3;   // layer1a, ktile 1
    {
        const int m = (mtb) * 16 + n16;
        const int kb0 = quad * 8, kb1 = 32 + quad * 8;
        a00_0 = ldA0(Whh0, Wih0, bih0, bhh0, m, kb0);
        a01_0 = ldA0(Whh0, Wih0, bih0, bhh0, m, kb1);
        aa0_0 = ldA1a(Wih1, bih1, bhh1, m, kb0);
        aa1_0 = ldA1a(Wih1, bih1, bhh1, m, kb1);
    }
    {
        const int m = (mtb + 1) * 16 + n16;
        const int kb0 = quad * 8, kb1 = 32 + quad * 8;
        a00_1 = ldA0(Whh0, Wih0, bih0, bhh0, m, kb0);
        a01_1 = ldA0(Whh0, Wih0, bih0, bhh0, m, kb1);
        aa0_1 = ldA1a(Wih1, bih1, bhh1, m, kb0);
        aa1_1 = ldA1a(Wih1, bih1, bhh1, m, kb1);
    }
    {
        const int m = (mtb + 2) * 16 + n16;
        const int kb0 = quad * 8, kb1 = 32 + quad * 8;
        a00_2 = ldA0(Whh0, Wih0, bih0, bhh0, m, kb0);
        a01_2 = ldA0(Whh0, Wih0, bih0, bhh0, m, kb1);
        aa0_2 = ldA1a(Wih1, bih1, bhh1, m, kb0);
        aa1_2 = ldA1a(Wih1, bih1, bhh1, m, kb1);
    }
    if (3 < nmt) {
        const int m = (mtb + 3) * 16 + n16;
        const int kb0 = quad * 8, kb1 = 32 + quad * 8;
        a00_3 = ldA0(Whh0, Wih0, bih0, bhh0, m, kb0);
        a01_3 = ldA0(Whh0, Wih0, bih0, bhh0, m, kb1);
        aa0_3 = ldA1a(Wih1, bih1, bhh1, m, kb0);
        aa1_3 = ldA1a(Wih1, bih1, bhh1, m, kb1);
    }

    __syncthreads();
    // specials in B: k=63 -> 1.0 (bias lane), k=62 -> x(0); only cols 0..NB-1
    if (tid < NB) {
        BPH[(64 + 48 + tid) * 8 + 7] = (f16)1.f;
        BPH[(64 + 48 + tid) * 8 + 6] = (f16)xg[tid * T_SEQ + 0];
    }
    __syncthreads();

    float cA = 0.f, cB = 0.f;           // one (unit,batch) pair per thread now
    const f16x8* BPF = (const f16x8*)BPH;
    const f16x8* APF = (const f16x8*)AP1b;

#define MFMA16(A, B, C) __builtin_amdgcn_mfma_f32_16x16x32_f16((A), (B), (C), 0, 0, 0)

#define P0MT(I) if ((I) < nmt) { \
    v4f C = {0.f, 0.f, 0.f, 0.f}; \
    C = MFMA16(a00_##I, B0, C); \
    C = MFMA16(a01_##I, B1, C); \
    float* gp = gbuf0 + n16 * GS + (mtb + (I)) * 16 + quad * 4; \
    if (n16 < NB) { gp[0] = C[0]; gp[1] = C[1]; gp[2] = C[2]; gp[3] = C[3]; } }

#define P2MT(I) if ((I) < nmt) { \
    v4f C = {0.f, 0.f, 0.f, 0.f}; \
    C = MFMA16(aa0_##I, B0, C); \
    C = MFMA16(aa1_##I, B1, C); \
    f16x8 Ab0 = APF[((mtb + (I)) * 2 + 0) * 64 + lane]; \
    f16x8 Ab1 = APF[((mtb + (I)) * 2 + 1) * 64 + lane]; \
    C = MFMA16(Ab0, B2, C); \
    C = MFMA16(Ab1, B3, C); \
    float* gp = gbuf1 + n16 * GS + (mtb + (I)) * 16 + quad * 4; \
    if (n16 < NB) { gp[0] = C[0]; gp[1] = C[1]; gp[2] = C[2]; gp[3] = C[3]; } }

    // update: thread tid -> (unit uu, batch nn); preacts COMPLETE (bias/x in MFMA)
#define UPD(GB, CS, KOFF, STASH) { \
    if (tid < HID * NB) { \
        const int uu = tid >> 2, nn = tid & 3; \
        const float qi = GB[nn * GS +        uu]; \
        const float qf = GB[nn * GS +  52 +  uu]; \
        const float qg = GB[nn * GS + 104 +  uu]; \
        const float qo = GB[nn * GS + 156 +  uu]; \
        const float gi = 1.f / (1.f + __expf(-qi)); \
        const float gf = 1.f / (1.f + __expf(-qf)); \
        const float gg = 2.f / (1.f + __expf(-2.f * qg)) - 1.f; \
        const float go = 1.f / (1.f + __expf(-qo)); \
        CS = fmaf(gf, CS, gi * gg); \
        const float hh = go * (2.f / (1.f + __expf(-2.f * CS)) - 1.f); \
        const int k = (KOFF) + uu; \
        BPH[((k >> 5) * 64 + ((k & 31) >> 3) * 16 + nn) * 8 + (k & 7)] = (f16)hh; \
        STASH \
    } }

    #pragma clang loop unroll(disable)
    for (int t = 0; t < T_SEQ; ++t) {
        // ---- P0: layer0 preacts = [Whh0|wx|b0] @ [hA(t-1);x(t);1] -> gbuf0 ----
        {
            f16x8 B0 = BPF[0 * 64 + lane];
            f16x8 B1 = BPF[1 * 64 + lane];
            P0MT(0) P0MT(1) P0MT(2) P0MT(3)
        }
        __syncthreads();   // B1: gbuf0 complete

        // ---- P1: layer0 update -> hA(t) into B slots k=0..49; prefetch x(t+1) ----
        UPD(gbuf0, cA, 0, {})
        if (tid < NB && t < T_SEQ - 1)
            BPH[(64 + 48 + tid) * 8 + 6] = (f16)xg[tid * T_SEQ + t + 1];
        __syncthreads();   // B2: hA(t), x(t+1) visible

        // ---- P2: layer1 preacts = [Wih1|b1]@[hA(t);..;1] + Whh1@hB(t-1) -> gbuf1 ----
        {
            f16x8 B0 = BPF[0 * 64 + lane];
            f16x8 B1 = BPF[1 * 64 + lane];
            f16x8 B2 = BPF[2 * 64 + lane];
            f16x8 B3 = BPF[3 * 64 + lane];
            P2MT(0) P2MT(1) P2MT(2) P2MT(3)
        }
        __syncthreads();   // B3: gbuf1 complete

        // ---- P3: layer1 update -> hB(t) into B slots k=64..113 (no trailing barrier:
        //      P0(t+1) touches only gbuf0 + B0/B1; gbuf1 WAR covered by B1,B2(t+1);
        //      hB written here is next READ at P2(t+1), after B2(t+1)) ----
        UPD(gbuf1, cB, 64, { if (t == T_SEQ - 1) gbuf0[nn * GS + uu] = hh; })
    }
    __syncthreads();   // final fp32 hB (stashed in gbuf0) visible

    // ---- classifier: out[n][c] = hB[n] . Wfc[c] + bfc[c] ----
    if (tid < NB * 2) {
        const int nn = tid >> 1, c = tid & 1;
        float acc = bfc[c];
        #pragma unroll
        for (int u = 0; u < HID; ++u)
            acc = fmaf(Wfc[c * HID + u], gbuf0[nn * GS + u], acc);
        out[(bb0 + nn) * 2 + c] = acc;
    }
}

extern "C" void kernel_launch(void* const* d_in, const int* in_sizes, int n_in,
                              void* d_out, int out_size, void* d_ws, size_t ws_size,
                              hipStream_t stream) {
    const float* x    = (const float*)d_in[0];
    const float* Wih0 = (const float*)d_in[1];
    const float* Whh0 = (const float*)d_in[2];
    const float* bih0 = (const float*)d_in[3];
    const float* bhh0 = (const float*)d_in[4];
    const float* Wih1 = (const float*)d_in[5];
    const float* Whh1 = (const float*)d_in[6];
    const float* bih1 = (const float*)d_in[7];
    const float* bhh1 = (const float*)d_in[8];
    const float* Wfc  = (const float*)d_in[9];
    const float* bfc  = (const float*)d_in[10];
    float* out = (float*)d_out;

    const int B = in_sizes[0] / T_SEQ;   // D == 1
    const int grid = B / NB;             // 2048/4 = 512 blocks -> 2 blocks/CU

    hipLaunchKernelGGL(lstm2_mfma, dim3(grid), dim3(BLK), 0, stream,
                       x, Wih0, Whh0, bih0, bhh0, Wih1, Whh1, bih1, bhh1,
                       Wfc, bfc, out);
}